// Round 4
// baseline (409.542 us; speedup 1.0000x reference)
//
#include <hip/hip_runtime.h>
#include <math.h>

#define NH 12
#define HD 32
#define GN 48
#define TK 96
#define NB 2
#define NN 1600
#define CC 384
#define BHN (NB*NH)          // 24
#define QKV_COLS (3*NH*HD)   // 1152
#define NQ (BHN*NN)          // 38400 total (b,h,n) queries

// ---------------------------------------------------------------------------
// GEMM: out = A[M,K] @ B[N,K]^T   (both row-major; B rows are output cols)
// MODE 0: scatter epilogue into q/k/v [B,h,N,d]   MODE 1: plain store [M,N]
// ---------------------------------------------------------------------------
template<int MODE>
__global__ __launch_bounds__(256)
void gemm_tile(const float* __restrict__ A, const float* __restrict__ B,
               float* __restrict__ o0, float* __restrict__ o1, float* __restrict__ o2,
               int M, int N, int K)
{
    __shared__ float As[16][64];
    __shared__ float Bs[16][64];
    const int tid = threadIdx.x;
    const int tx = tid & 15, ty = tid >> 4;
    const int m0 = blockIdx.y * 64, n0 = blockIdx.x * 64;
    const int lr = tid >> 2;          // tile row 0..63
    const int lc = (tid & 3) * 4;     // k-seg 0,4,8,12
    float acc[4][4] = {};

    for (int k0 = 0; k0 < K; k0 += 16) {
        float4 av = *(const float4*)&A[(m0 + lr) * K + k0 + lc];
        float4 bv = *(const float4*)&B[(n0 + lr) * K + k0 + lc];
        __syncthreads();   // previous iter's compute done before overwrite
        As[lc+0][lr] = av.x; As[lc+1][lr] = av.y; As[lc+2][lr] = av.z; As[lc+3][lr] = av.w;
        Bs[lc+0][lr] = bv.x; Bs[lc+1][lr] = bv.y; Bs[lc+2][lr] = bv.z; Bs[lc+3][lr] = bv.w;
        __syncthreads();
        #pragma unroll
        for (int kk = 0; kk < 16; ++kk) {
            float4 a4 = *(const float4*)&As[kk][ty*4];
            float4 b4 = *(const float4*)&Bs[kk][tx*4];
            float a[4] = {a4.x, a4.y, a4.z, a4.w};
            float b[4] = {b4.x, b4.y, b4.z, b4.w};
            #pragma unroll
            for (int i = 0; i < 4; ++i)
                #pragma unroll
                for (int j = 0; j < 4; ++j)
                    acc[i][j] = fmaf(a[i], b[j], acc[i][j]);
        }
    }

    if (MODE == 0) {
        #pragma unroll
        for (int i = 0; i < 4; ++i) {
            int row = m0 + ty*4 + i;
            int b  = row / NN;
            int nn = row - b * NN;
            #pragma unroll
            for (int j = 0; j < 4; ++j) {
                int col = n0 + tx*4 + j;
                int which = col / CC;          // uniform per tile (384 % 64 == 0)
                int rem = col - which * CC;
                int hh = rem >> 5, dd = rem & 31;
                float* dst = (which == 0) ? o0 : (which == 1) ? o1 : o2;
                dst[((b*NH + hh)*NN + nn)*HD + dd] = acc[i][j];
            }
        }
    } else {
        #pragma unroll
        for (int i = 0; i < 4; ++i) {
            int row = m0 + ty*4 + i;
            float4 st = make_float4(acc[i][0], acc[i][1], acc[i][2], acc[i][3]);
            *(float4*)&o0[row * N + n0 + tx*4] = st;
        }
    }
}

// ---------------------------------------------------------------------------
// Kernel 2: per-query group argmax (gidx), strict > == jnp.argmax tie-break
// ---------------------------------------------------------------------------
__global__ __launch_bounds__(256)
void group_route(const float* __restrict__ q, const float* __restrict__ wgp,
                 int* __restrict__ gidx)
{
    int t = blockIdx.x * 256 + threadIdx.x;   // [0, NQ)
    int bh = t / NN;
    int hh = bh % NH;
    const float* qp = q + t * HD;
    float qr[HD];
    #pragma unroll
    for (int i = 0; i < HD; i += 4) {
        float4 x = *(const float4*)&qp[i];
        qr[i] = x.x; qr[i+1] = x.y; qr[i+2] = x.z; qr[i+3] = x.w;
    }
    float best = -INFINITY; int bg = 0;
    for (int g = 0; g < GN; ++g) {
        const float* gp = wgp + hh*GN*HD + g*HD;
        float s = 0.f;
        #pragma unroll
        for (int i = 0; i < HD; i += 4) {
            float4 w = *(const float4*)&gp[i];
            s += qr[i]*w.x + qr[i+1]*w.y + qr[i+2]*w.z + qr[i+3]*w.w;
        }
        if (s > best) { best = s; bg = g; }
    }
    gidx[t] = bg;
}

// ---------------------------------------------------------------------------
// Kernel 3: per (b,h,g): deterministic q_mean, qmw scores, RADIX-SELECT top-96
// + emit per-group query buckets (qperm/qoff/qcnt) for the attention kernel.
// ---------------------------------------------------------------------------
__global__ __launch_bounds__(256)
void qmean_topk(const float* __restrict__ q, const float* __restrict__ k,
                const int* __restrict__ gidx, int* __restrict__ topk,
                int* __restrict__ qperm, int* __restrict__ qoff,
                int* __restrict__ qcnt)
{
    __shared__ unsigned keys[NN];      // order-preserving uint transform of score
    __shared__ unsigned hist_s[256];
    __shared__ unsigned sfx_s[256];
    __shared__ float part[8][HD];
    __shared__ int   cnts[8];
    __shared__ float qm_s[HD];
    __shared__ unsigned wtot_s[4];
    __shared__ int   bstar_s;
    __shared__ unsigned sub_s;
    __shared__ int   cnt_s, eq_s;
    __shared__ int   off_s, pos_s;

    const int bid = blockIdx.x;     // [0, BHN*GN)
    const int g = bid % GN, bh = bid / GN;
    const int tid = threadIdx.x;
    const int s = tid >> 5, dd = tid & 31;
    const int lane = tid & 63, wv = tid >> 6;

    const int*   gx = gidx + bh * NN;
    const float* qb = q + bh * NN * HD;
    const float* kb = k + bh * NN * HD;

    if (tid == 0) { off_s = 0; pos_s = 0; }

    // --- phase A: deterministic group-mean of q ---
    float p = 0.f; int c = 0;
    for (int n = s; n < NN; n += 8) {
        if (gx[n] == g) { p += qb[n*HD + dd]; c++; }
    }
    part[s][dd] = p;
    if (dd == 0) cnts[s] = c;
    __syncthreads();
    if (tid < HD) {
        float sum = 0.f; int ct = 0;
        for (int ss = 0; ss < 8; ++ss) { sum += part[ss][tid]; ct += cnts[ss]; }
        qm_s[tid] = (ct > 0) ? sum / (float)ct : 0.0f;
    }

    // --- phase A2: query bucket for this group (offset = #queries in groups<g) ---
    int mo = 0;
    for (int n = tid; n < NN; n += 256) mo += (gx[n] < g);
    atomicAdd(&off_s, mo);
    __syncthreads();
    for (int n = tid; n < NN; n += 256) {
        if (gx[n] == g) {
            int ppos = atomicAdd(&pos_s, 1);
            qperm[bh*NN + off_s + ppos] = n;
        }
    }
    // (pos_s finalized at the next barrier; written to qcnt at the end)

    // --- phase B: keys[m] = sortable(q_mean . k[m]) ---
    __syncthreads();
    if (tid == 0) { qoff[bid] = off_s; qcnt[bid] = pos_s; }
    float qr[HD];
    #pragma unroll
    for (int i = 0; i < HD; i += 4) {
        float4 x = *(const float4*)&qm_s[i];
        qr[i] = x.x; qr[i+1] = x.y; qr[i+2] = x.z; qr[i+3] = x.w;
    }
    for (int m = tid; m < NN; m += 256) {
        const float* kp = kb + m * HD;
        float sc = 0.f;
        #pragma unroll
        for (int i = 0; i < HD; i += 4) {
            float4 w = *(const float4*)&kp[i];
            sc += qr[i]*w.x + qr[i+1]*w.y + qr[i+2]*w.z + qr[i+3]*w.w;
        }
        unsigned u = __float_as_uint(sc);
        u = (u & 0x80000000u) ? ~u : (u | 0x80000000u);
        keys[m] = u;
    }
    __syncthreads();

    // --- phase C: 4-pass radix select for the top-96 threshold key ---
    unsigned prefix = 0;
    unsigned r = TK;                 // how many still to take at current level
    #pragma unroll
    for (int pass = 0; pass < 4; ++pass) {
        const int shift = 24 - 8*pass;
        hist_s[tid] = 0;
        __syncthreads();
        for (int m = tid; m < NN; m += 256) {
            unsigned u = keys[m];
            bool match = (pass == 0) || ((u >> (shift + 8)) == (prefix >> (shift + 8)));
            if (match) atomicAdd(&hist_s[(u >> shift) & 255u], 1u);
        }
        __syncthreads();
        // suffix sum over 256 bins: wave-local shfl scan + cross-wave totals
        unsigned v = hist_s[tid];
        #pragma unroll
        for (int off = 1; off < 64; off <<= 1) {
            unsigned o = __shfl_down(v, off);
            if (lane + off < 64) v += o;
        }
        if (lane == 0) wtot_s[wv] = v;
        __syncthreads();
        unsigned add = 0;
        for (int ww = wv + 1; ww < 4; ++ww) add += wtot_s[ww];
        sfx_s[tid] = v + add;
        __syncthreads();
        // find pivot bin: largest b with sfx[b] >= r  (unique)
        unsigned mysfx = sfx_s[tid];
        unsigned nxt = (tid == 255) ? 0u : sfx_s[tid+1];
        if (mysfx >= r && nxt < r) { bstar_s = tid; sub_s = nxt; }
        __syncthreads();
        prefix |= ((unsigned)bstar_s) << shift;
        r -= sub_s;                  // uniform across block (LDS broadcast)
        __syncthreads();
    }
    const unsigned P = prefix;       // exact 96th-largest key; r = # equals to take

    // --- collect: key > P all in; key == P fill smallest-index first ---
    int* tko = topk + bid * TK;
    if (tid == 0) { cnt_s = 0; eq_s = 0; }
    __syncthreads();
    for (int m = tid; m < NN; m += 256) {
        unsigned u = keys[m];
        if (u > P) { int pos = atomicAdd(&cnt_s, 1); tko[pos] = m; }
        else if (u == P) atomicAdd(&eq_s, 1);
    }
    __syncthreads();
    if ((unsigned)eq_s == r) {
        for (int m = tid; m < NN; m += 256) {
            if (keys[m] == P) { int pos = atomicAdd(&cnt_s, 1); tko[pos] = m; }
        }
    } else if (tid == 0) {
        // degenerate ties (e.g. empty group -> all scores equal): lowest indices
        int pos = cnt_s; unsigned need = r;
        for (int m = 0; m < NN && need; ++m) {
            if (keys[m] == P) { tko[pos++] = m; --need; }
        }
    }
}

// ---------------------------------------------------------------------------
// Kernel 4 (v3): group-bucketed attention. One block per (b,h,g); K/V top-96
// rows staged in LDS once, then all queries of the group (8 lanes/query,
// 32 queries per pass) score against LDS. Phase-1 reads staggered
// ((dl+ii)&7) -> conflict-free; phase-2 reads are same-address broadcasts.
// ---------------------------------------------------------------------------
__global__ __launch_bounds__(256)
void sparse_attn3(const float* __restrict__ q, const float* __restrict__ k,
                  const float* __restrict__ v, const int* __restrict__ topk,
                  const int* __restrict__ qperm, const int* __restrict__ qoff,
                  const int* __restrict__ qcnt, float* __restrict__ out)
{
    __shared__ float Ks[TK*HD];   // 12 KB
    __shared__ float Vs[TK*HD];   // 12 KB

    const int bid = blockIdx.x;   // bh*GN + g
    const int bh = bid / GN;
    const int nq = qcnt[bid];
    if (nq == 0) return;          // uniform per block
    const int off = qoff[bid];
    const int tid = threadIdx.x;

    const int* __restrict__ tk = topk + bid*TK;
    const float* __restrict__ kb = k + bh*NN*HD;
    const float* __restrict__ vb = v + bh*NN*HD;

    // stage K,V: 768 float4 each; 8 consecutive lanes fetch one 128B row
    for (int idx = tid; idx < TK*8; idx += 256) {
        int row = idx >> 3, ch = idx & 7;
        int r = tk[row];
        ((float4*)Ks)[idx] = *(const float4*)&kb[r*HD + ch*4];
        ((float4*)Vs)[idx] = *(const float4*)&vb[r*HD + ch*4];
    }
    __syncthreads();

    const float scale = 0.17677669529663687f;   // 32^-0.5
    const int qs = tid >> 3;            // query slot 0..31
    const int dl = tid & 7;             // lane in 8-lane group
    const int lb = (tid & 63) & ~7;     // wave-lane base of the group
    const int b = bh / NH, hh = bh - b*NH;
    const float* __restrict__ qbase = q + bh*NN*HD;
    const int* __restrict__ qlist = qperm + bh*NN + off;

    for (int it0 = 0; it0 < nq; it0 += 32) {
        const int qi = it0 + qs;
        const bool act = (qi < nq);
        const int nn = act ? qlist[qi] : 0;

        float qr[HD];
        const float* qp = qbase + nn*HD;
        #pragma unroll
        for (int i = 0; i < HD; i += 4) {
            float4 x = *(const float4*)&qp[i];
            qr[i] = x.x; qr[i+1] = x.y; qr[i+2] = x.z; qr[i+3] = x.w;
        }

        // phase 1: 12 scores per lane from LDS K (staggered chunks)
        float sc[12];
        #pragma unroll
        for (int t = 0; t < 12; ++t) {
            const int j = t*8 + dl;
            float s0 = 0.f, s1 = 0.f, s2 = 0.f, s3 = 0.f;
            #pragma unroll
            for (int ii = 0; ii < 8; ++ii) {
                const int ch = (dl + ii) & 7;
                float4 w = *(const float4*)&Ks[j*HD + ch*4];
                s0 = fmaf(qr[ch*4+0], w.x, s0);
                s1 = fmaf(qr[ch*4+1], w.y, s1);
                s2 = fmaf(qr[ch*4+2], w.z, s2);
                s3 = fmaf(qr[ch*4+3], w.w, s3);
            }
            sc[t] = ((s0 + s1) + (s2 + s3)) * scale;
        }

        // softmax across the 96 scores (8-lane shfl reduce)
        float m = -INFINITY;
        #pragma unroll
        for (int t = 0; t < 12; ++t) m = fmaxf(m, sc[t]);
        #pragma unroll
        for (int o = 1; o < 8; o <<= 1) m = fmaxf(m, __shfl_xor(m, o));
        float l = 0.f;
        #pragma unroll
        for (int t = 0; t < 12; ++t) { sc[t] = __expf(sc[t] - m); l += sc[t]; }
        #pragma unroll
        for (int o = 1; o < 8; o <<= 1) l += __shfl_xor(l, o);
        const float inv = 1.0f / l;
        #pragma unroll
        for (int t = 0; t < 12; ++t) sc[t] *= inv;

        // phase 2: weighted V sum; lane owns dims 4dl..4dl+3 (LDS broadcast)
        float a0 = 0.f, a1 = 0.f, a2 = 0.f, a3 = 0.f;
        #pragma unroll
        for (int t = 0; t < 12; ++t) {
            #pragma unroll
            for (int jj = 0; jj < 8; ++jj) {
                const float p = __shfl(sc[t], lb + jj);
                float4 vv = *(const float4*)&Vs[(t*8 + jj)*HD + dl*4];
                a0 = fmaf(p, vv.x, a0);
                a1 = fmaf(p, vv.y, a1);
                a2 = fmaf(p, vv.z, a2);
                a3 = fmaf(p, vv.w, a3);
            }
        }

        if (act) {
            float* op = out + (b*NN + nn)*CC + hh*HD + dl*4;
            *(float4*)op = make_float4(a0, a1, a2, a3);
        }
    }
}

// ---------------------------------------------------------------------------
extern "C" void kernel_launch(void* const* d_in, const int* in_sizes, int n_in,
                              void* d_out, int out_size, void* d_ws, size_t ws_size,
                              hipStream_t stream)
{
    const float* x      = (const float*)d_in[0];   // [B,H,W,C] = [3200, 384]
    const float* w_qkv  = (const float*)d_in[1];   // [1152, 384]
    const float* w_gp   = (const float*)d_in[2];   // [48, 384] -> (12,48,32)
    const float* w_proj = (const float*)d_in[3];   // [384, 384]
    float* out = (float*)d_out;                    // [B,H,W,C]

    float* ws = (float*)d_ws;
    float* q        = ws;                 // [B,h,N,d] 1228800
    float* kk       = ws + 1228800;
    float* vv       = ws + 2457600;
    float* attn_out = ws + 3686400;       // [B,N,h*d] 1228800
    int*   iws      = (int*)(ws + 4915200);
    int*   gidx     = iws;                // 38400
    int*   topk     = iws + 38400;        // 110592
    int*   qperm    = iws + 38400 + 110592;            // 38400
    int*   qoff     = iws + 38400 + 110592 + 38400;    // 1152
    int*   qcnt     = qoff + 1152;                     // 1152

    // 1) QKV projection, scatter into q/k/v
    gemm_tile<0><<<dim3(QKV_COLS/64, (NB*NN)/64), 256, 0, stream>>>(
        x, w_qkv, q, kk, vv, NB*NN, QKV_COLS, CC);

    // 2) query -> group routing
    group_route<<<NQ/256, 256, 0, stream>>>(q, w_gp, gidx);

    // 3) group means + top-96 (radix select) + query buckets
    qmean_topk<<<BHN*GN, 256, 0, stream>>>(q, kk, gidx, topk, qperm, qoff, qcnt);

    // 4) group-bucketed sparse attention (K/V in LDS)
    sparse_attn3<<<BHN*GN, 256, 0, stream>>>(q, kk, vv, topk, qperm, qoff, qcnt, attn_out);

    // 5) output projection
    gemm_tile<1><<<dim3(CC/64, (NB*NN)/64), 256, 0, stream>>>(
        attn_out, w_proj, out, nullptr, nullptr, NB*NN, CC, CC);
}

// Round 5
// 303.097 us; speedup vs baseline: 1.3512x; 1.3512x over previous
//
#include <hip/hip_runtime.h>
#include <math.h>

#define NH 12
#define HD 32
#define GN 48
#define TK 96
#define NB 2
#define NN 1600
#define CC 384
#define BHN (NB*NH)          // 24
#define QKV_COLS (3*NH*HD)   // 1152
#define NQ (BHN*NN)          // 38400 total (b,h,n) queries

// ---------------------------------------------------------------------------
// GEMM: out = A[M,K] @ B[N,K]^T   (both row-major; B rows are output cols)
// MODE 0: scatter epilogue into q/k/v [B,h,N,d]   MODE 1: plain store [M,N]
// ---------------------------------------------------------------------------
template<int MODE>
__global__ __launch_bounds__(256)
void gemm_tile(const float* __restrict__ A, const float* __restrict__ B,
               float* __restrict__ o0, float* __restrict__ o1, float* __restrict__ o2,
               int M, int N, int K)
{
    __shared__ float As[16][64];
    __shared__ float Bs[16][64];
    const int tid = threadIdx.x;
    const int tx = tid & 15, ty = tid >> 4;
    const int m0 = blockIdx.y * 64, n0 = blockIdx.x * 64;
    const int lr = tid >> 2;          // tile row 0..63
    const int lc = (tid & 3) * 4;     // k-seg 0,4,8,12
    float acc[4][4] = {};

    for (int k0 = 0; k0 < K; k0 += 16) {
        float4 av = *(const float4*)&A[(m0 + lr) * K + k0 + lc];
        float4 bv = *(const float4*)&B[(n0 + lr) * K + k0 + lc];
        __syncthreads();   // previous iter's compute done before overwrite
        As[lc+0][lr] = av.x; As[lc+1][lr] = av.y; As[lc+2][lr] = av.z; As[lc+3][lr] = av.w;
        Bs[lc+0][lr] = bv.x; Bs[lc+1][lr] = bv.y; Bs[lc+2][lr] = bv.z; Bs[lc+3][lr] = bv.w;
        __syncthreads();
        #pragma unroll
        for (int kk = 0; kk < 16; ++kk) {
            float4 a4 = *(const float4*)&As[kk][ty*4];
            float4 b4 = *(const float4*)&Bs[kk][tx*4];
            float a[4] = {a4.x, a4.y, a4.z, a4.w};
            float b[4] = {b4.x, b4.y, b4.z, b4.w};
            #pragma unroll
            for (int i = 0; i < 4; ++i)
                #pragma unroll
                for (int j = 0; j < 4; ++j)
                    acc[i][j] = fmaf(a[i], b[j], acc[i][j]);
        }
    }

    if (MODE == 0) {
        #pragma unroll
        for (int i = 0; i < 4; ++i) {
            int row = m0 + ty*4 + i;
            int b  = row / NN;
            int nn = row - b * NN;
            #pragma unroll
            for (int j = 0; j < 4; ++j) {
                int col = n0 + tx*4 + j;
                int which = col / CC;          // uniform per tile (384 % 64 == 0)
                int rem = col - which * CC;
                int hh = rem >> 5, dd = rem & 31;
                float* dst = (which == 0) ? o0 : (which == 1) ? o1 : o2;
                dst[((b*NH + hh)*NN + nn)*HD + dd] = acc[i][j];
            }
        }
    } else {
        #pragma unroll
        for (int i = 0; i < 4; ++i) {
            int row = m0 + ty*4 + i;
            float4 st = make_float4(acc[i][0], acc[i][1], acc[i][2], acc[i][3]);
            *(float4*)&o0[row * N + n0 + tx*4] = st;
        }
    }
}

// ---------------------------------------------------------------------------
// Kernel 2: per-query group argmax (gidx), strict > == jnp.argmax tie-break
// ---------------------------------------------------------------------------
__global__ __launch_bounds__(256)
void group_route(const float* __restrict__ q, const float* __restrict__ wgp,
                 int* __restrict__ gidx)
{
    int t = blockIdx.x * 256 + threadIdx.x;   // [0, NQ)
    int bh = t / NN;
    int hh = bh % NH;
    const float* qp = q + t * HD;
    float qr[HD];
    #pragma unroll
    for (int i = 0; i < HD; i += 4) {
        float4 x = *(const float4*)&qp[i];
        qr[i] = x.x; qr[i+1] = x.y; qr[i+2] = x.z; qr[i+3] = x.w;
    }
    float best = -INFINITY; int bg = 0;
    for (int g = 0; g < GN; ++g) {
        const float* gp = wgp + hh*GN*HD + g*HD;
        float s = 0.f;
        #pragma unroll
        for (int i = 0; i < HD; i += 4) {
            float4 w = *(const float4*)&gp[i];
            s += qr[i]*w.x + qr[i+1]*w.y + qr[i+2]*w.z + qr[i+3]*w.w;
        }
        if (s > best) { best = s; bg = g; }
    }
    gidx[t] = bg;
}

// ---------------------------------------------------------------------------
// Kernel 3: per (b,h,g): deterministic q_mean, qmw scores, RADIX-SELECT top-96
// ---------------------------------------------------------------------------
__global__ __launch_bounds__(256)
void qmean_topk(const float* __restrict__ q, const float* __restrict__ k,
                const int* __restrict__ gidx, int* __restrict__ topk)
{
    __shared__ unsigned keys[NN];      // order-preserving uint transform of score
    __shared__ unsigned hist_s[256];
    __shared__ unsigned sfx_s[256];
    __shared__ float part[8][HD];
    __shared__ int   cnts[8];
    __shared__ float qm_s[HD];
    __shared__ unsigned wtot_s[4];
    __shared__ int   bstar_s;
    __shared__ unsigned sub_s;
    __shared__ int   cnt_s, eq_s;

    const int bid = blockIdx.x;     // [0, BHN*GN)
    const int g = bid % GN, bh = bid / GN;
    const int tid = threadIdx.x;
    const int s = tid >> 5, dd = tid & 31;
    const int lane = tid & 63, wv = tid >> 6;

    const int*   gx = gidx + bh * NN;
    const float* qb = q + bh * NN * HD;
    const float* kb = k + bh * NN * HD;

    // --- phase A: deterministic group-mean of q ---
    float p = 0.f; int c = 0;
    for (int n = s; n < NN; n += 8) {
        if (gx[n] == g) { p += qb[n*HD + dd]; c++; }
    }
    part[s][dd] = p;
    if (dd == 0) cnts[s] = c;
    __syncthreads();
    if (tid < HD) {
        float sum = 0.f; int ct = 0;
        for (int ss = 0; ss < 8; ++ss) { sum += part[ss][tid]; ct += cnts[ss]; }
        qm_s[tid] = (ct > 0) ? sum / (float)ct : 0.0f;
    }
    __syncthreads();

    // --- phase B: keys[m] = sortable(q_mean . k[m]) ---
    float qr[HD];
    #pragma unroll
    for (int i = 0; i < HD; i += 4) {
        float4 x = *(const float4*)&qm_s[i];
        qr[i] = x.x; qr[i+1] = x.y; qr[i+2] = x.z; qr[i+3] = x.w;
    }
    for (int m = tid; m < NN; m += 256) {
        const float* kp = kb + m * HD;
        float sc = 0.f;
        #pragma unroll
        for (int i = 0; i < HD; i += 4) {
            float4 w = *(const float4*)&kp[i];
            sc += qr[i]*w.x + qr[i+1]*w.y + qr[i+2]*w.z + qr[i+3]*w.w;
        }
        unsigned u = __float_as_uint(sc);
        u = (u & 0x80000000u) ? ~u : (u | 0x80000000u);
        keys[m] = u;
    }
    __syncthreads();

    // --- phase C: 4-pass radix select for the top-96 threshold key ---
    unsigned prefix = 0;
    unsigned r = TK;                 // how many still to take at current level
    #pragma unroll
    for (int pass = 0; pass < 4; ++pass) {
        const int shift = 24 - 8*pass;
        hist_s[tid] = 0;
        __syncthreads();
        for (int m = tid; m < NN; m += 256) {
            unsigned u = keys[m];
            bool match = (pass == 0) || ((u >> (shift + 8)) == (prefix >> (shift + 8)));
            if (match) atomicAdd(&hist_s[(u >> shift) & 255u], 1u);
        }
        __syncthreads();
        // suffix sum over 256 bins: wave-local shfl scan + cross-wave totals
        unsigned v = hist_s[tid];
        #pragma unroll
        for (int off = 1; off < 64; off <<= 1) {
            unsigned o = __shfl_down(v, off);
            if (lane + off < 64) v += o;
        }
        if (lane == 0) wtot_s[wv] = v;
        __syncthreads();
        unsigned add = 0;
        for (int ww = wv + 1; ww < 4; ++ww) add += wtot_s[ww];
        sfx_s[tid] = v + add;
        __syncthreads();
        // find pivot bin: largest b with sfx[b] >= r  (unique)
        unsigned mysfx = sfx_s[tid];
        unsigned nxt = (tid == 255) ? 0u : sfx_s[tid+1];
        if (mysfx >= r && nxt < r) { bstar_s = tid; sub_s = nxt; }
        __syncthreads();
        prefix |= ((unsigned)bstar_s) << shift;
        r -= sub_s;                  // uniform across block (LDS broadcast)
        __syncthreads();
    }
    const unsigned P = prefix;       // exact 96th-largest key; r = # equals to take

    // --- collect: key > P all in; key == P fill smallest-index first ---
    int* tko = topk + bid * TK;
    if (tid == 0) { cnt_s = 0; eq_s = 0; }
    __syncthreads();
    for (int m = tid; m < NN; m += 256) {
        unsigned u = keys[m];
        if (u > P) { int pos = atomicAdd(&cnt_s, 1); tko[pos] = m; }
        else if (u == P) atomicAdd(&eq_s, 1);
    }
    __syncthreads();
    if ((unsigned)eq_s == r) {
        for (int m = tid; m < NN; m += 256) {
            if (keys[m] == P) { int pos = atomicAdd(&cnt_s, 1); tko[pos] = m; }
        }
    } else if (tid == 0) {
        // degenerate ties (e.g. empty group -> all scores equal): lowest indices
        int pos = cnt_s; unsigned need = r;
        for (int m = 0; m < NN && need; ++m) {
            if (keys[m] == P) { tko[pos++] = m; --need; }
        }
    }
}

// ---------------------------------------------------------------------------
// Kernel 4 (v4): like v2 (8 lanes/query, zero LDS, zero barriers) but with
// COALESCED K reads: per key, the 8 lanes of a query group each load one
// 16B chunk of the 128B K-row (1 cache line per key per group, vs 8 in v2);
// each lane holds only q[4dl..4dl+3], dot partials reduced by 3 shfl_xor.
// Phase 2 (V accumulate) is row-coalesced as in v2.
// ---------------------------------------------------------------------------
__global__ __launch_bounds__(256)
void sparse_attn4(const float* __restrict__ q, const float* __restrict__ k,
                  const float* __restrict__ v, const int* __restrict__ gidx,
                  const int* __restrict__ topk, float* __restrict__ out)
{
    const float scale = 0.17677669529663687f;   // 32^-0.5
    const int tid = threadIdx.x;
    const int qs = tid >> 3;              // query slot in block, 0..31
    const int dl = tid & 7;               // lane within query group, 0..7
    const int Q  = blockIdx.x * 32 + qs;  // [0, NQ)
    const int bh = Q / NN, nn = Q - bh * NN;
    const int lb = (tid & 63) & ~7;       // wave-lane base of this 8-lane group

    const int g = gidx[Q];
    const int* __restrict__ tk = topk + (bh*GN + g) * TK;
    const float* __restrict__ kb = k + bh * NN * HD;
    const float* __restrict__ vb = v + bh * NN * HD;

    // this lane's 4 dims of q
    float4 q4 = *(const float4*)&q[Q * HD + dl*4];

    // key indices: lane dl holds keys t*8+dl
    int ki[12];
    #pragma unroll
    for (int t = 0; t < 12; ++t) ki[t] = tk[t*8 + dl];

    // --- phase 1: scores, one cache line per key per group ---
    float sc[12];
    #pragma unroll
    for (int t = 0; t < 12; ++t) {
        float keep = 0.f;
        #pragma unroll
        for (int u = 0; u < 8; ++u) {
            int kj = __shfl(ki[t], lb + u);          // key index t*8+u
            float4 w = *(const float4*)&kb[kj*HD + dl*4];
            float p = fmaf(q4.x, w.x, fmaf(q4.y, w.y, fmaf(q4.z, w.z, q4.w*w.w)));
            p += __shfl_xor(p, 1);
            p += __shfl_xor(p, 2);
            p += __shfl_xor(p, 4);                   // all 8 lanes: full dot
            if (u == dl) keep = p;                   // lane dl keeps key t*8+dl
        }
        sc[t] = keep * scale;
    }

    // softmax over the 96 scores (8-lane shfl reduce)
    float m = -INFINITY;
    #pragma unroll
    for (int t = 0; t < 12; ++t) m = fmaxf(m, sc[t]);
    #pragma unroll
    for (int off = 1; off < 8; off <<= 1) m = fmaxf(m, __shfl_xor(m, off));
    float l = 0.f;
    #pragma unroll
    for (int t = 0; t < 12; ++t) { sc[t] = __expf(sc[t] - m); l += sc[t]; }
    #pragma unroll
    for (int off = 1; off < 8; off <<= 1) l += __shfl_xor(l, off);
    float inv = 1.0f / l;
    #pragma unroll
    for (int t = 0; t < 12; ++t) sc[t] *= inv;

    // --- phase 2: weighted V gather; lane owns dims 4dl..4dl+3 ---
    float a0 = 0.f, a1 = 0.f, a2 = 0.f, a3 = 0.f;
    #pragma unroll
    for (int t = 0; t < 12; ++t) {
        #pragma unroll
        for (int jj = 0; jj < 8; ++jj) {
            int   kj = __shfl(ki[t], lb + jj);   // broadcast within 8-lane group
            float p  = __shfl(sc[t], lb + jj);
            float4 vv = *(const float4*)&vb[kj*HD + dl*4];
            a0 = fmaf(p, vv.x, a0);
            a1 = fmaf(p, vv.y, a1);
            a2 = fmaf(p, vv.z, a2);
            a3 = fmaf(p, vv.w, a3);
        }
    }

    const int b = bh / NH, hh = bh - b*NH;
    float* op = out + (b*NN + nn)*CC + hh*HD + dl*4;
    *(float4*)op = make_float4(a0, a1, a2, a3);
}

// ---------------------------------------------------------------------------
extern "C" void kernel_launch(void* const* d_in, const int* in_sizes, int n_in,
                              void* d_out, int out_size, void* d_ws, size_t ws_size,
                              hipStream_t stream)
{
    const float* x      = (const float*)d_in[0];   // [B,H,W,C] = [3200, 384]
    const float* w_qkv  = (const float*)d_in[1];   // [1152, 384]
    const float* w_gp   = (const float*)d_in[2];   // [48, 384] -> (12,48,32)
    const float* w_proj = (const float*)d_in[3];   // [384, 384]
    float* out = (float*)d_out;                    // [B,H,W,C]

    float* ws = (float*)d_ws;
    float* q        = ws;                 // [B,h,N,d] 1228800
    float* kk       = ws + 1228800;
    float* vv       = ws + 2457600;
    float* attn_out = ws + 3686400;       // [B,N,h*d] 1228800
    int*   iws      = (int*)(ws + 4915200);
    int*   gidx     = iws;                // 38400
    int*   topk     = iws + 38400;        // 110592

    // 1) QKV projection, scatter into q/k/v
    gemm_tile<0><<<dim3(QKV_COLS/64, (NB*NN)/64), 256, 0, stream>>>(
        x, w_qkv, q, kk, vv, NB*NN, QKV_COLS, CC);

    // 2) query -> group routing
    group_route<<<NQ/256, 256, 0, stream>>>(q, w_gp, gidx);

    // 3) group means + group->key top-96 (radix select)
    qmean_topk<<<BHN*GN, 256, 0, stream>>>(q, kk, gidx, topk);

    // 4) sparse masked attention (coalesced two-phase)
    sparse_attn4<<<NQ/32, 256, 0, stream>>>(q, kk, vv, gidx, topk, attn_out);

    // 5) output projection
    gemm_tile<1><<<dim3(CC/64, (NB*NN)/64), 256, 0, stream>>>(
        attn_out, w_proj, out, nullptr, nullptr, NB*NN, CC, CC);
}